// Round 10
// baseline (315.028 us; speedup 1.0000x reference)
//
#include <hip/hip_runtime.h>
#include <cstddef>

// AdaBP LDPC decoder, MI355X (gfx950) — fused, register-v2c, check-major LDS.
// One workgroup per batch column, all T=30 iterations in-kernel.
// v2c state lives in registers (thread-private col segments). LDS holds two
// check-major SoA arrays [slot][m] (48 KB each): fs_s = copysign(log-tanh,
// lam) written scattered by the variable phase; c2v_s updated contiguously by
// the check phase. Check phase is 100% bank-conflict-free (round 9 showed
// 1.1e7 conflict cycles from scattered check-phase gathers).

namespace {
constexpr int N  = 4096;
constexpr int M  = 2048;
constexpr int CD = 3;
constexpr int RD = 6;
constexpr int E  = N * CD;   // 12288
constexpr int B  = 128;
constexpr int T  = 30;
constexpr float CLIP    = 15.0f;
constexpr float FEPS    = 1e-6f;
constexpr float MIN_ABS = 6.1180465e-07f;  // -log(tanh(15/2))
constexpr int TPB = 1024;
constexpr int VPT = N / TPB;  // 4 vars per thread
constexpr int CPT = M / TPB;  // 2 checks per thread

// ---- build edge -> (slot, check) LDS index: vlist[e] = slot*M + m ----
__global__ __launch_bounds__(256) void k_build(const int* __restrict__ row_idx,
                                               int* __restrict__ cnt,
                                               int* __restrict__ vlist) {
  int e = blockIdx.x * 256 + threadIdx.x;
  if (e < E) {
    int m    = row_idx[e];
    int slot = atomicAdd(&cnt[m], 1);  // exactly RD edges per check
    vlist[e] = slot * M + m;           // SoA check-major address
  }
}

// ---- the whole decoder for one batch column ----
__global__ __launch_bounds__(TPB, 4) void k_fused(
    const float* __restrict__ chn,
    const float* __restrict__ gW1, const float* __restrict__ gb1,
    const float* __restrict__ gW2, const float* __restrict__ gb2,
    const float* __restrict__ iW1, const float* __restrict__ ib1,
    const float* __restrict__ iW2, const float* __restrict__ ib2,
    const float* __restrict__ eW1, const float* __restrict__ eb1,
    const float* __restrict__ eW2, const float* __restrict__ eb2,
    const int* __restrict__ vlist, float* __restrict__ outT) {
  __shared__ float fs_s[RD * M];   // 48 KB: copysign(lt, lam) per edge
  __shared__ float c2v_s[RD * M];  // 48 KB: C2V messages, check-major SoA
  __shared__ float red[32];

  const int tid  = threadIdx.x;
  const int b    = blockIdx.x;   // batch column
  const int wid  = tid >> 6;
  const int lane = tid & 63;

  for (int i = tid; i < RD * M; i += TPB) c2v_s[i] = 0.f;

  // load my chn values; accumulate Eng partial
  float ch[VPT];
  float local = 0.f;
#pragma unroll
  for (int i = 0; i < VPT; ++i) {
    int v = tid + i * TPB;
    ch[i] = chn[(size_t)v * B + b];
    local += ch[i] * ch[i];
  }
#pragma unroll
  for (int off = 32; off > 0; off >>= 1) local += __shfl_down(local, off, 64);
  if (lane == 0) red[wid] = local;
  __syncthreads();
  if (tid == 0) {
    float tot = 0.f;
    for (int w = 0; w < 16; ++w) tot += red[w];
    red[16] = tot * (1.f / (float)N);  // Eng
  }
  __syncthreads();
  // waves 0..2 evaluate the three 1-20-1 MLPs (lane j handles hidden unit j)
  if (wid < 3) {
    float Eng = red[16];
    float snr = 10.f * log10f(Eng / (1.f + sqrtf(1.f + Eng)) * 0.5f);
    const float *W1, *b1, *W2, *b2;
    if (wid == 0)      { W1 = gW1; b1 = gb1; W2 = gW2; b2 = gb2; }
    else if (wid == 1) { W1 = iW1; b1 = ib1; W2 = iW2; b2 = ib2; }
    else               { W1 = eW1; b1 = eb1; W2 = eW2; b2 = eb2; }
    float h = 0.f;
    if (lane < 20) h = fmaxf(snr * W1[lane] + b1[lane], 0.f) * W2[lane];
#pragma unroll
    for (int off = 32; off > 0; off >>= 1) h += __shfl_down(h, off, 64);
    if (lane == 0) red[20 + wid] = 1.f / (1.f + expf(-(h + b2[0])));
  }
  __syncthreads();
  const float g   = red[20];
  const float wiv = red[21];
  const float wev = red[22];
  const float omg = 1.f - g;
  float ell[VPT];
#pragma unroll
  for (int i = 0; i < VPT; ++i) ell[i] = wiv * ch[i];

  // edge -> LDS slot addresses (static thereafter) + register v2c state
  int vl[VPT][CD];
#pragma unroll
  for (int i = 0; i < VPT; ++i) {
    int v = tid + i * TPB;
#pragma unroll
    for (int j = 0; j < CD; ++j) vl[i][j] = vlist[v * CD + j];
  }
  float v2c[VPT][CD] = {};
  __syncthreads();

// per-edge variable-phase body (static J so everything stays in registers)
#define VAR_EDGE(i, J, WJ)                                              \
  {                                                                     \
    float nv = fmaf(omg, v2c[i][J], g * (es - (WJ)));                   \
    v2c[i][J] = nv;                                                     \
    float l   = fminf(fmaxf(nv, -CLIP), CLIP);                          \
    float al  = fmaxf(fabsf(l), MIN_ABS);                               \
    float ea  = __expf(al);                                             \
    float r   = __builtin_amdgcn_rcpf(ea + 1.f);                        \
    float u   = 2.f * r;  /* = 1 - tanh(al/2) */                        \
    float ltp = -u * fmaf(u, fmaf(u, 0.33333333f, 0.5f), 1.f);          \
    float ltl = __logf((ea - 1.f) * r);                                 \
    float lte = (u < 0.04f) ? ltp : ltl; /* log(tanh(al/2)), < 0 */     \
    fs_s[vl[i][J]] = (l < 0.f) ? lte : -lte; /* sign bit = (lam<0) */   \
  }

// per-edge check-phase body: contiguous at slot K, check m
#define CHK_EDGE(K)                                                     \
  {                                                                     \
    int   c   = neg - n##K;                                             \
    float amp = lts - l##K; /* < 0 */                                   \
    float ea2 = __expf(amp);                                            \
    float emp = amp * fmaf(amp, fmaf(amp, 0.16666667f, 0.5f), 1.f);     \
    float em  = (amp > -0.04f) ? emp : (ea2 - 1.f); /* expm1(amp) */    \
    float den = fmaf(FEPS, ea2, -em);        /* 1 - x  (> 0) */         \
    float num = fmaf(-FEPS, ea2, 2.f + em);  /* 1 + x */                \
    float cnew = __logf(num * __builtin_amdgcn_rcpf(den));              \
    if (c & 1) cnew = -cnew;                                            \
    c2v_s[K * M + m] = fmaf(omg, c2v_s[K * M + m], g * cnew);           \
  }

  for (int t = 0; t < T; ++t) {
    // ---- variable phase: scattered c2v reads, v2c in regs, scattered fs ----
#pragma unroll
    for (int i = 0; i < VPT; ++i) {
      int v    = tid + i * TPB;
      float w0 = wev * c2v_s[vl[i][0]];
      float w1 = wev * c2v_s[vl[i][1]];
      float w2 = wev * c2v_s[vl[i][2]];
      float es = ell[i] + w0 + w1 + w2;
      if (t > 0) outT[((size_t)b * T + (t - 1)) * N + v] = es;
      VAR_EDGE(i, 0, w0)
      VAR_EDGE(i, 1, w1)
      VAR_EDGE(i, 2, w2)
    }
    __syncthreads();
    // ---- check phase: fully contiguous (lane t <-> check m) ----
#pragma unroll
    for (int i = 0; i < CPT; ++i) {
      int m = tid + i * TPB;
      float f0 = fs_s[0 * M + m], f1 = fs_s[1 * M + m], f2 = fs_s[2 * M + m];
      float f3 = fs_s[3 * M + m], f4 = fs_s[4 * M + m], f5 = fs_s[5 * M + m];
      float l0 = -fabsf(f0), l1 = -fabsf(f1), l2 = -fabsf(f2);
      float l3 = -fabsf(f3), l4 = -fabsf(f4), l5 = -fabsf(f5);
      int n0 = f0 < 0.f, n1 = f1 < 0.f, n2 = f2 < 0.f;
      int n3 = f3 < 0.f, n4 = f4 < 0.f, n5 = f5 < 0.f;
      float lts = ((l0 + l1) + (l2 + l3)) + (l4 + l5);
      int   neg = ((n0 + n1) + (n2 + n3)) + (n4 + n5);
      CHK_EDGE(0) CHK_EDGE(1) CHK_EDGE(2)
      CHK_EDGE(3) CHK_EDGE(4) CHK_EDGE(5)
    }
    __syncthreads();
  }
  // ---- final output row: out[T-1] = ell + full weighted col sum ----
#pragma unroll
  for (int i = 0; i < VPT; ++i) {
    int v   = tid + i * TPB;
    float s = wev * (c2v_s[vl[i][0]] + c2v_s[vl[i][1]] + c2v_s[vl[i][2]]);
    outT[((size_t)b * T + (T - 1)) * N + v] = ell[i] + s;
  }
#undef VAR_EDGE
#undef CHK_EDGE
}

// ---- transpose out_T[b][t][v] -> out[t][v][b], tiled through LDS ----
__global__ __launch_bounds__(256) void k_tr(const float* __restrict__ outT,
                                            float* __restrict__ out) {
  __shared__ float tile[128 * 65];  // [b][v-tile], padded
  int t   = blockIdx.y;
  int v0  = blockIdx.x * 64;
  int tid = threadIdx.x;
#pragma unroll
  for (int r = 0; r < 32; ++r) {
    int bb = r * 4 + (tid >> 6);
    int v  = tid & 63;
    tile[bb * 65 + v] = outT[((size_t)bb * T + t) * N + v0 + v];
  }
  __syncthreads();
#pragma unroll
  for (int r = 0; r < 32; ++r) {
    int v  = r * 2 + (tid >> 7);
    int bb = tid & 127;
    // out is never re-read: non-temporal store keeps it out of L2
    __builtin_nontemporal_store(tile[bb * 65 + v],
                                &out[((size_t)t * N + v0 + v) * B + bb]);
  }
}

}  // namespace

extern "C" void kernel_launch(void* const* d_in, const int* in_sizes, int n_in,
                              void* d_out, int out_size, void* d_ws,
                              size_t ws_size, hipStream_t stream) {
  const float* chn = (const float*)d_in[0];
  const float* gW1 = (const float*)d_in[1];
  const float* gb1 = (const float*)d_in[2];
  const float* gW2 = (const float*)d_in[3];
  const float* gb2 = (const float*)d_in[4];
  const float* iW1 = (const float*)d_in[5];
  const float* ib1 = (const float*)d_in[6];
  const float* iW2 = (const float*)d_in[7];
  const float* ib2 = (const float*)d_in[8];
  const float* eW1 = (const float*)d_in[9];
  const float* eb1 = (const float*)d_in[10];
  const float* eW2 = (const float*)d_in[11];
  const float* eb2 = (const float*)d_in[12];
  const int* row_idx = (const int*)d_in[13];
  // d_in[14] (col_idx) = repeat(arange(N),3) by construction -> implicit.
  float* out = (float*)d_out;

  // workspace layout
  float* outT  = (float*)d_ws;                      // B*T*N floats (63 MB)
  int*   cnt   = (int*)(outT + (size_t)B * T * N);  // M ints
  int*   vlist = cnt + M;                           // E ints

  hipMemsetAsync(cnt, 0, M * sizeof(int), stream);
  k_build<<<(E + 255) / 256, 256, 0, stream>>>(row_idx, cnt, vlist);
  k_fused<<<B, TPB, 0, stream>>>(chn, gW1, gb1, gW2, gb2, iW1, ib1, iW2, ib2,
                                 eW1, eb1, eW2, eb2, vlist, outT);
  dim3 tg(N / 64, T);
  k_tr<<<tg, 256, 0, stream>>>(outT, out);
}

// Round 14
// 244.507 us; speedup vs baseline: 1.2884x; 1.2884x over previous
//
#include <hip/hip_runtime.h>
#include <cstddef>

// AdaBP LDPC decoder, MI355X (gfx950) — fused, u-domain check math.
// One workgroup per batch column, all T=30 iterations in-kernel.
// v2c in registers (thread-private col segments). c2v in check-owner
// registers; LDS holds two check-major SoA arrays [slot][m] (48 KB each):
//   us_s : u = 1 - tanh(|lam|/2), sign bit = (lam < 0)   (var -> check)
//   c2v_s: We * c2v messages                              (check -> var)
// Check phase uses stable LOO prefix products in u-domain:
//   1 - t1..tk = u1 + t1*(1 - t2..tk)  (positive terms, no cancellation)
//   den = (1 - P_loo) + eps*P_loo ; num = 2 - den ; cnew = log(num/den)
// -> per edge: var = {exp, rcp}, check = {rcp, log}. No expm1/log1p, no
// selects (round 4/9 showed VALU-instruction-bound; round 10 falsified the
// bank-conflict theory).

namespace {
constexpr int N  = 4096;
constexpr int M  = 2048;
constexpr int CD = 3;
constexpr int RD = 6;
constexpr int E  = N * CD;   // 12288
constexpr int B  = 128;
constexpr int T  = 30;
constexpr float CLIP    = 15.0f;
constexpr float FEPS    = 1e-6f;
constexpr float MIN_ABS = 6.1180465e-07f;  // -log(tanh(15/2))
constexpr int TPB = 1024;
constexpr int VPT = N / TPB;  // 4 vars per thread
constexpr int CPT = M / TPB;  // 2 checks per thread

// ---- build edge -> (slot, check) LDS index: vlist[e] = slot*M + m ----
__global__ __launch_bounds__(256) void k_build(const int* __restrict__ row_idx,
                                               int* __restrict__ cnt,
                                               int* __restrict__ vlist) {
  int e = blockIdx.x * 256 + threadIdx.x;
  if (e < E) {
    int m    = row_idx[e];
    int slot = atomicAdd(&cnt[m], 1);  // exactly RD edges per check
    vlist[e] = slot * M + m;           // SoA check-major address
  }
}

// ---- the whole decoder for one batch column ----
__global__ __launch_bounds__(TPB, 4) void k_fused(
    const float* __restrict__ chn,
    const float* __restrict__ gW1, const float* __restrict__ gb1,
    const float* __restrict__ gW2, const float* __restrict__ gb2,
    const float* __restrict__ iW1, const float* __restrict__ ib1,
    const float* __restrict__ iW2, const float* __restrict__ ib2,
    const float* __restrict__ eW1, const float* __restrict__ eb1,
    const float* __restrict__ eW2, const float* __restrict__ eb2,
    const int* __restrict__ vlist, float* __restrict__ outT) {
  __shared__ float us_s[RD * M];   // 48 KB: signed u per edge (var->check)
  __shared__ float c2v_s[RD * M];  // 48 KB: We*c2v per edge (check->var)
  __shared__ float red[32];

  const int tid  = threadIdx.x;
  const int b    = blockIdx.x;   // batch column
  const int wid  = tid >> 6;
  const int lane = tid & 63;

  for (int i = tid; i < RD * M; i += TPB) c2v_s[i] = 0.f;

  // load my chn values; accumulate Eng partial
  float ch[VPT];
  float local = 0.f;
#pragma unroll
  for (int i = 0; i < VPT; ++i) {
    int v = tid + i * TPB;
    ch[i] = chn[(size_t)v * B + b];
    local += ch[i] * ch[i];
  }
#pragma unroll
  for (int off = 32; off > 0; off >>= 1) local += __shfl_down(local, off, 64);
  if (lane == 0) red[wid] = local;
  __syncthreads();
  if (tid == 0) {
    float tot = 0.f;
    for (int w = 0; w < 16; ++w) tot += red[w];
    red[16] = tot * (1.f / (float)N);  // Eng
  }
  __syncthreads();
  // waves 0..2 evaluate the three 1-20-1 MLPs (lane j handles hidden unit j)
  if (wid < 3) {
    float Eng = red[16];
    float snr = 10.f * log10f(Eng / (1.f + sqrtf(1.f + Eng)) * 0.5f);
    const float *W1, *b1, *W2, *b2;
    if (wid == 0)      { W1 = gW1; b1 = gb1; W2 = gW2; b2 = gb2; }
    else if (wid == 1) { W1 = iW1; b1 = ib1; W2 = iW2; b2 = ib2; }
    else               { W1 = eW1; b1 = eb1; W2 = eW2; b2 = eb2; }
    float h = 0.f;
    if (lane < 20) h = fmaxf(snr * W1[lane] + b1[lane], 0.f) * W2[lane];
#pragma unroll
    for (int off = 32; off > 0; off >>= 1) h += __shfl_down(h, off, 64);
    if (lane == 0) red[20 + wid] = 1.f / (1.f + expf(-(h + b2[0])));
  }
  __syncthreads();
  const float g   = red[20];
  const float wiv = red[21];
  const float wev = red[22];
  const float omg = 1.f - g;
  float ell[VPT];
#pragma unroll
  for (int i = 0; i < VPT; ++i) ell[i] = wiv * ch[i];

  // edge -> LDS slot addresses (static thereafter) + register message state
  int vl[VPT][CD];
#pragma unroll
  for (int i = 0; i < VPT; ++i) {
    int v = tid + i * TPB;
#pragma unroll
    for (int j = 0; j < CD; ++j) vl[i][j] = vlist[v * CD + j];
  }
  float v2c[VPT][CD] = {};       // V2C state (variable-owner registers)
  float c2v[CPT][RD] = {};       // C2V state (check-owner registers)
  __syncthreads();

// per-edge variable-phase body: update v2c, publish signed u
#define VAR_EDGE(i, J, WJ)                                              \
  {                                                                     \
    float nv  = fmaf(omg, v2c[i][J], g * (es - (WJ)));                  \
    v2c[i][J] = nv;                                                     \
    float l   = fminf(fmaxf(nv, -CLIP), CLIP);                          \
    float al  = fmaxf(fabsf(l), MIN_ABS);                               \
    float u   = 2.f * __builtin_amdgcn_rcpf(__expf(al) + 1.f);          \
    us_s[vl[i][J]] = (l < 0.f) ? -u : u; /* u = 1 - tanh(al/2) > 0 */   \
  }

  for (int t = 0; t < T; ++t) {
    // ---- variable phase: scattered c2v reads, v2c in regs, publish u ----
#pragma unroll
    for (int i = 0; i < VPT; ++i) {
      int v    = tid + i * TPB;
      float w0 = c2v_s[vl[i][0]];   // pre-scaled by We
      float w1 = c2v_s[vl[i][1]];
      float w2 = c2v_s[vl[i][2]];
      float es = ell[i] + ((w0 + w1) + w2);
      if (t > 0) outT[((size_t)b * T + (t - 1)) * N + v] = es;
      VAR_EDGE(i, 0, w0)
      VAR_EDGE(i, 1, w1)
      VAR_EDGE(i, 2, w2)
    }
    __syncthreads();
    // ---- check phase: contiguous (lane t <-> check m), u-domain LOO ----
#pragma unroll
    for (int i = 0; i < CPT; ++i) {
      int m = tid + i * TPB;
      float u[RD], tt[RD];
      unsigned int sb[RD], s_all = 0u;
#pragma unroll
      for (int k = 0; k < RD; ++k) {
        float usv = us_s[k * M + m];
        float a   = fabsf(usv);
        u[k]  = a;
        tt[k] = 1.f - a;  // tanh(al/2)
        sb[k] = __float_as_uint(usv) & 0x80000000u;
        s_all ^= sb[k];
      }
      // prefix (1 - prod) / prod over edges [0, k)
      float omp[RD + 1], Pp[RD + 1];
      omp[0] = 0.f; Pp[0] = 1.f;
#pragma unroll
      for (int k = 0; k < RD; ++k) {
        omp[k + 1] = fmaf(Pp[k], u[k], omp[k]);
        Pp[k + 1]  = Pp[k] * tt[k];
      }
      // suffix running (oms, Ps) over (k, RD); iterate k = RD-1 .. 0
      float oms = 0.f, Ps = 1.f;
#pragma unroll
      for (int k = RD - 1; k >= 0; --k) {
        float om_loo = fmaf(Pp[k], oms, omp[k]);  // 1 - P_loo (stable)
        float P_loo  = Pp[k] * Ps;
        float den  = fmaf(FEPS, P_loo, om_loo);   // 1 - x, x = P_loo(1-eps)
        float num  = 2.f - den;                   // 1 + x (exact identity)
        float cnew = __logf(num * __builtin_amdgcn_rcpf(den));  // > 0
        cnew = __uint_as_float(__float_as_uint(cnew) ^ (s_all ^ sb[k]));
        float nc   = fmaf(omg, c2v[i][k], g * cnew);
        c2v[i][k]  = nc;
        c2v_s[k * M + m] = wev * nc;              // publish pre-scaled
        oms = fmaf(tt[k], oms, u[k]);             // extend suffix to [k, RD)
        Ps *= tt[k];
      }
    }
    __syncthreads();
  }
  // ---- final output row: out[T-1] = ell + full weighted col sum ----
#pragma unroll
  for (int i = 0; i < VPT; ++i) {
    int v   = tid + i * TPB;
    float s = (c2v_s[vl[i][0]] + c2v_s[vl[i][1]]) + c2v_s[vl[i][2]];
    outT[((size_t)b * T + (T - 1)) * N + v] = ell[i] + s;
  }
#undef VAR_EDGE
}

// ---- transpose out_T[b][t][v] -> out[t][v][b], tiled through LDS ----
__global__ __launch_bounds__(256) void k_tr(const float* __restrict__ outT,
                                            float* __restrict__ out) {
  __shared__ float tile[128 * 65];  // [b][v-tile], padded
  int t   = blockIdx.y;
  int v0  = blockIdx.x * 64;
  int tid = threadIdx.x;
#pragma unroll
  for (int r = 0; r < 32; ++r) {
    int bb = r * 4 + (tid >> 6);
    int v  = tid & 63;
    tile[bb * 65 + v] = outT[((size_t)bb * T + t) * N + v0 + v];
  }
  __syncthreads();
#pragma unroll
  for (int r = 0; r < 32; ++r) {
    int v  = r * 2 + (tid >> 7);
    int bb = tid & 127;
    // out is never re-read: non-temporal store keeps it out of L2
    __builtin_nontemporal_store(tile[bb * 65 + v],
                                &out[((size_t)t * N + v0 + v) * B + bb]);
  }
}

}  // namespace

extern "C" void kernel_launch(void* const* d_in, const int* in_sizes, int n_in,
                              void* d_out, int out_size, void* d_ws,
                              size_t ws_size, hipStream_t stream) {
  const float* chn = (const float*)d_in[0];
  const float* gW1 = (const float*)d_in[1];
  const float* gb1 = (const float*)d_in[2];
  const float* gW2 = (const float*)d_in[3];
  const float* gb2 = (const float*)d_in[4];
  const float* iW1 = (const float*)d_in[5];
  const float* ib1 = (const float*)d_in[6];
  const float* iW2 = (const float*)d_in[7];
  const float* ib2 = (const float*)d_in[8];
  const float* eW1 = (const float*)d_in[9];
  const float* eb1 = (const float*)d_in[10];
  const float* eW2 = (const float*)d_in[11];
  const float* eb2 = (const float*)d_in[12];
  const int* row_idx = (const int*)d_in[13];
  // d_in[14] (col_idx) = repeat(arange(N),3) by construction -> implicit.
  float* out = (float*)d_out;

  // workspace layout
  float* outT  = (float*)d_ws;                      // B*T*N floats (63 MB)
  int*   cnt   = (int*)(outT + (size_t)B * T * N);  // M ints
  int*   vlist = cnt + M;                           // E ints

  hipMemsetAsync(cnt, 0, M * sizeof(int), stream);
  k_build<<<(E + 255) / 256, 256, 0, stream>>>(row_idx, cnt, vlist);
  k_fused<<<B, TPB, 0, stream>>>(chn, gW1, gb1, gW2, gb2, iW1, ib1, iW2, ib2,
                                 eW1, eb1, eW2, eb2, vlist, outT);
  dim3 tg(N / 64, T);
  k_tr<<<tg, 256, 0, stream>>>(outT, out);
}

// Round 15
// 242.082 us; speedup vs baseline: 1.3013x; 1.0100x over previous
//
#include <hip/hip_runtime.h>
#include <cstddef>

// AdaBP LDPC decoder, MI355X (gfx950) — fused, u-domain, single-LDS-array.
// One workgroup per batch column, all T=30 iterations in-kernel.
// v2c in variable-owner registers; c2v in check-owner registers.
// ONE edge-major LDS array x_s[m*12+slot] (96 KB) time-shares two meanings:
//   after var phase:   signed u = ±(1 - tanh(|lam|/2))   (var -> check)
//   after check phase: We * c2v                           (check -> var)
// Legal because each slot is touched by exactly one thread per phase, and
// that thread reads the old meaning before writing the new one.
// Pad 6->12 slots => 48-B row stride, 16-B aligned: check phase accesses its
// 6 slots as float4+float2 (ds b128+b64, bank-uniform) => LDS ops 48->32 per
// thread-iter. Graph build (slot assignment) is done in-block via LDS
// atomics (consistency only needed within the block) => no k_build/memset.

namespace {
constexpr int N  = 4096;
constexpr int M  = 2048;
constexpr int CD = 3;
constexpr int RD = 6;
constexpr int B  = 128;
constexpr int T  = 30;
constexpr int PAD = 12;            // slots per check row (6 used, 16B-aligned)
constexpr float CLIP    = 15.0f;
constexpr float FEPS    = 1e-6f;
constexpr float MIN_ABS = 6.1180465e-07f;  // -log(tanh(15/2))
constexpr int TPB = 1024;
constexpr int VPT = N / TPB;  // 4 vars per thread
constexpr int CPT = M / TPB;  // 2 checks per thread

// ---- the whole decoder for one batch column ----
__global__ __launch_bounds__(TPB) void k_fused(
    const float* __restrict__ chn,
    const float* __restrict__ gW1, const float* __restrict__ gb1,
    const float* __restrict__ gW2, const float* __restrict__ gb2,
    const float* __restrict__ iW1, const float* __restrict__ ib1,
    const float* __restrict__ iW2, const float* __restrict__ ib2,
    const float* __restrict__ eW1, const float* __restrict__ eb1,
    const float* __restrict__ eW2, const float* __restrict__ eb2,
    const int* __restrict__ row_idx, float* __restrict__ outT) {
  __shared__ float x_s[M * PAD];   // 96 KB: dual-meaning edge array
  __shared__ int   cnt_s[M];       // 8 KB: build counters
  __shared__ float red[32];

  const int tid  = threadIdx.x;
  const int b    = blockIdx.x;   // batch column
  const int wid  = tid >> 6;
  const int lane = tid & 63;

  // zero message state (c2v meaning) + build counters
  for (int i = tid; i < M * PAD; i += TPB) x_s[i] = 0.f;
  for (int i = tid; i < M; i += TPB) cnt_s[i] = 0;

  // load my chn values; accumulate Eng partial
  float ch[VPT];
  float local = 0.f;
#pragma unroll
  for (int i = 0; i < VPT; ++i) {
    int v = tid + i * TPB;
    ch[i] = chn[(size_t)v * B + b];
    local += ch[i] * ch[i];
  }
#pragma unroll
  for (int off = 32; off > 0; off >>= 1) local += __shfl_down(local, off, 64);
  if (lane == 0) red[wid] = local;
  __syncthreads();   // covers: zero x_s/cnt_s, red partials
  if (tid == 0) {
    float tot = 0.f;
    for (int w = 0; w < 16; ++w) tot += red[w];
    red[16] = tot * (1.f / (float)N);  // Eng
  }
  __syncthreads();
  // waves 0..2 evaluate the three 1-20-1 MLPs (lane j handles hidden unit j)
  if (wid < 3) {
    float Eng = red[16];
    float snr = 10.f * log10f(Eng / (1.f + sqrtf(1.f + Eng)) * 0.5f);
    const float *W1, *b1, *W2, *b2;
    if (wid == 0)      { W1 = gW1; b1 = gb1; W2 = gW2; b2 = gb2; }
    else if (wid == 1) { W1 = iW1; b1 = ib1; W2 = iW2; b2 = ib2; }
    else               { W1 = eW1; b1 = eb1; W2 = eW2; b2 = eb2; }
    float h = 0.f;
    if (lane < 20) h = fmaxf(snr * W1[lane] + b1[lane], 0.f) * W2[lane];
#pragma unroll
    for (int off = 32; off > 0; off >>= 1) h += __shfl_down(h, off, 64);
    if (lane == 0) red[20 + wid] = 1.f / (1.f + expf(-(h + b2[0])));
  }
  // in-block graph build: slot assignment via LDS atomics. Any per-block
  // assignment is valid (LOO sums are commutative; slot identity links the
  // var-owner and check-owner through the same x_s address).
  int vl[VPT][CD];
#pragma unroll
  for (int i = 0; i < VPT; ++i) {
    int v = tid + i * TPB;
#pragma unroll
    for (int j = 0; j < CD; ++j) {
      int m    = row_idx[v * CD + j];
      int slot = atomicAdd(&cnt_s[m], 1);  // exactly RD=6 edges per check
      vl[i][j] = m * PAD + slot;
    }
  }
  __syncthreads();   // MLP results ready; x_s zeros visible
  const float g   = red[20];
  const float wiv = red[21];
  const float wev = red[22];
  const float omg = 1.f - g;
  float ell[VPT];
#pragma unroll
  for (int i = 0; i < VPT; ++i) ell[i] = wiv * ch[i];

  float v2c[VPT][CD] = {};       // V2C state (variable-owner registers)
  float c2v[CPT][RD] = {};       // C2V state (check-owner registers)

// per-edge variable-phase body: read We*c2v (WJ), update v2c, publish ±u
#define VAR_EDGE(i, J, WJ)                                              \
  {                                                                     \
    float nv  = fmaf(omg, v2c[i][J], g * (es - (WJ)));                  \
    v2c[i][J] = nv;                                                     \
    float l   = fminf(fmaxf(nv, -CLIP), CLIP);                          \
    float al  = fmaxf(fabsf(l), MIN_ABS);                               \
    float u   = 2.f * __builtin_amdgcn_rcpf(__expf(al) + 1.f);          \
    x_s[vl[i][J]] = (l < 0.f) ? -u : u; /* u = 1 - tanh(al/2) > 0 */    \
  }

  for (int t = 0; t < T; ++t) {
    // ---- variable phase: scattered b32 reads (We*c2v), publish ±u ----
#pragma unroll
    for (int i = 0; i < VPT; ++i) {
      int v    = tid + i * TPB;
      float w0 = x_s[vl[i][0]];
      float w1 = x_s[vl[i][1]];
      float w2 = x_s[vl[i][2]];
      float es = ell[i] + ((w0 + w1) + w2);
      if (t > 0) outT[((size_t)b * T + (t - 1)) * N + v] = es;
      VAR_EDGE(i, 0, w0)
      VAR_EDGE(i, 1, w1)
      VAR_EDGE(i, 2, w2)
    }
    __syncthreads();
    // ---- check phase: wide contiguous access, u-domain LOO products ----
#pragma unroll
    for (int i = 0; i < CPT; ++i) {
      int m = tid + i * TPB;
      float* row = &x_s[m * PAD];
      float4 q4 = *(const float4*)row;       // slots 0..3 (ds_read_b128)
      float2 q2 = *(const float2*)(row + 4); // slots 4..5 (ds_read_b64)
      float usv[RD] = {q4.x, q4.y, q4.z, q4.w, q2.x, q2.y};
      float u[RD], tt[RD];
      unsigned int sb[RD], s_all = 0u;
#pragma unroll
      for (int k = 0; k < RD; ++k) {
        float a = fabsf(usv[k]);
        u[k]  = a;
        tt[k] = 1.f - a;  // tanh(al/2)
        sb[k] = __float_as_uint(usv[k]) & 0x80000000u;
        s_all ^= sb[k];
      }
      // prefix (1 - prod) / prod over edges [0, k)
      float omp[RD + 1], Pp[RD + 1];
      omp[0] = 0.f; Pp[0] = 1.f;
#pragma unroll
      for (int k = 0; k < RD; ++k) {
        omp[k + 1] = fmaf(Pp[k], u[k], omp[k]);
        Pp[k + 1]  = Pp[k] * tt[k];
      }
      // suffix running (oms, Ps); iterate k = RD-1 .. 0
      float oms = 0.f, Ps = 1.f;
      float wout[RD];
#pragma unroll
      for (int k = RD - 1; k >= 0; --k) {
        float om_loo = fmaf(Pp[k], oms, omp[k]);  // 1 - P_loo (stable)
        float P_loo  = Pp[k] * Ps;
        float den  = fmaf(FEPS, P_loo, om_loo);   // 1 - x, x = P_loo(1-eps)
        float num  = 2.f - den;                   // 1 + x (exact identity)
        float cnew = __logf(num * __builtin_amdgcn_rcpf(den));  // > 0
        cnew = __uint_as_float(__float_as_uint(cnew) ^ (s_all ^ sb[k]));
        float nc   = fmaf(omg, c2v[i][k], g * cnew);
        c2v[i][k]  = nc;
        wout[k]    = wev * nc;                    // publish pre-scaled
        oms = fmaf(tt[k], oms, u[k]);             // extend suffix to [k, RD)
        Ps *= tt[k];
      }
      *(float4*)row       = make_float4(wout[0], wout[1], wout[2], wout[3]);
      *(float2*)(row + 4) = make_float2(wout[4], wout[5]);
    }
    __syncthreads();
  }
  // ---- final output row: out[T-1] = ell + full weighted col sum ----
#pragma unroll
  for (int i = 0; i < VPT; ++i) {
    int v   = tid + i * TPB;
    float s = (x_s[vl[i][0]] + x_s[vl[i][1]]) + x_s[vl[i][2]];
    outT[((size_t)b * T + (T - 1)) * N + v] = ell[i] + s;
  }
#undef VAR_EDGE
}

// ---- transpose out_T[b][t][v] -> out[t][v][b], tiled through LDS ----
__global__ __launch_bounds__(256) void k_tr(const float* __restrict__ outT,
                                            float* __restrict__ out) {
  __shared__ float tile[128 * 65];  // [b][v-tile], padded
  int t   = blockIdx.y;
  int v0  = blockIdx.x * 64;
  int tid = threadIdx.x;
#pragma unroll
  for (int r = 0; r < 32; ++r) {
    int bb = r * 4 + (tid >> 6);
    int v  = tid & 63;
    tile[bb * 65 + v] = outT[((size_t)bb * T + t) * N + v0 + v];
  }
  __syncthreads();
#pragma unroll
  for (int r = 0; r < 32; ++r) {
    int v  = r * 2 + (tid >> 7);
    int bb = tid & 127;
    // out is never re-read: non-temporal store keeps it out of L2
    __builtin_nontemporal_store(tile[bb * 65 + v],
                                &out[((size_t)t * N + v0 + v) * B + bb]);
  }
}

}  // namespace

extern "C" void kernel_launch(void* const* d_in, const int* in_sizes, int n_in,
                              void* d_out, int out_size, void* d_ws,
                              size_t ws_size, hipStream_t stream) {
  const float* chn = (const float*)d_in[0];
  const float* gW1 = (const float*)d_in[1];
  const float* gb1 = (const float*)d_in[2];
  const float* gW2 = (const float*)d_in[3];
  const float* gb2 = (const float*)d_in[4];
  const float* iW1 = (const float*)d_in[5];
  const float* ib1 = (const float*)d_in[6];
  const float* iW2 = (const float*)d_in[7];
  const float* ib2 = (const float*)d_in[8];
  const float* eW1 = (const float*)d_in[9];
  const float* eb1 = (const float*)d_in[10];
  const float* eW2 = (const float*)d_in[11];
  const float* eb2 = (const float*)d_in[12];
  const int* row_idx = (const int*)d_in[13];
  // d_in[14] (col_idx) = repeat(arange(N),3) by construction -> implicit.
  float* out = (float*)d_out;

  float* outT = (float*)d_ws;  // B*T*N floats (63 MB)

  k_fused<<<B, TPB, 0, stream>>>(chn, gW1, gb1, gW2, gb2, iW1, ib1, iW2, ib2,
                                 eW1, eb1, eW2, eb2, row_idx, outT);
  dim3 tg(N / 64, T);
  k_tr<<<tg, 256, 0, stream>>>(outT, out);
}

// Round 16
// 236.183 us; speedup vs baseline: 1.3338x; 1.0250x over previous
//
#include <hip/hip_runtime.h>
#include <cstddef>

// AdaBP LDPC decoder, MI355X (gfx950) — fused, u-domain, check-major LDS.
// One workgroup per batch column, all T=30 iterations in-kernel.
// v2c in variable-owner registers; c2v in check-owner registers.
// ONE check-major LDS array x_s[slot*M + m] (48 KB) time-shares two meanings:
//   after var phase:   signed u = ±(1 - tanh(|lam|/2))   (var -> check)
//   after check phase: We * c2v                           (check -> var)
// Legal because each slot is touched by exactly one thread per phase, and
// that thread reads the old meaning before writing the new one.
// Check-major => check phase is conflict-free b32 (consecutive m ->
// consecutive banks; round 15 measured the wide/edge-major variant WORSE:
// PAD=12 rows give 8-way-conflicted b128). Graph build is in-block via LDS
// atomics (slot consistency only needed within the block).

namespace {
constexpr int N  = 4096;
constexpr int M  = 2048;
constexpr int CD = 3;
constexpr int RD = 6;
constexpr int B  = 128;
constexpr int T  = 30;
constexpr float CLIP    = 15.0f;
constexpr float FEPS    = 1e-6f;
constexpr float MIN_ABS = 6.1180465e-07f;  // -log(tanh(15/2))
constexpr int TPB = 1024;
constexpr int VPT = N / TPB;  // 4 vars per thread
constexpr int CPT = M / TPB;  // 2 checks per thread

// ---- the whole decoder for one batch column ----
__global__ __launch_bounds__(TPB) void k_fused(
    const float* __restrict__ chn,
    const float* __restrict__ gW1, const float* __restrict__ gb1,
    const float* __restrict__ gW2, const float* __restrict__ gb2,
    const float* __restrict__ iW1, const float* __restrict__ ib1,
    const float* __restrict__ iW2, const float* __restrict__ ib2,
    const float* __restrict__ eW1, const float* __restrict__ eb1,
    const float* __restrict__ eW2, const float* __restrict__ eb2,
    const int* __restrict__ row_idx, float* __restrict__ outT) {
  __shared__ float x_s[RD * M];    // 48 KB: dual-meaning edge array
  __shared__ int   cnt_s[M];       // 8 KB: build counters
  __shared__ float red[32];

  const int tid  = threadIdx.x;
  const int b    = blockIdx.x;   // batch column
  const int wid  = tid >> 6;
  const int lane = tid & 63;

  // zero message state (c2v meaning) + build counters
  for (int i = tid; i < RD * M; i += TPB) x_s[i] = 0.f;
  for (int i = tid; i < M; i += TPB) cnt_s[i] = 0;

  // load my chn values; accumulate Eng partial
  float ch[VPT];
  float local = 0.f;
#pragma unroll
  for (int i = 0; i < VPT; ++i) {
    int v = tid + i * TPB;
    ch[i] = chn[(size_t)v * B + b];
    local += ch[i] * ch[i];
  }
#pragma unroll
  for (int off = 32; off > 0; off >>= 1) local += __shfl_down(local, off, 64);
  if (lane == 0) red[wid] = local;
  __syncthreads();   // covers: zero x_s/cnt_s, red partials
  if (tid == 0) {
    float tot = 0.f;
    for (int w = 0; w < 16; ++w) tot += red[w];
    red[16] = tot * (1.f / (float)N);  // Eng
  }
  __syncthreads();
  // waves 0..2 evaluate the three 1-20-1 MLPs (lane j handles hidden unit j)
  if (wid < 3) {
    float Eng = red[16];
    float snr = 10.f * log10f(Eng / (1.f + sqrtf(1.f + Eng)) * 0.5f);
    const float *W1, *b1, *W2, *b2;
    if (wid == 0)      { W1 = gW1; b1 = gb1; W2 = gW2; b2 = gb2; }
    else if (wid == 1) { W1 = iW1; b1 = ib1; W2 = iW2; b2 = ib2; }
    else               { W1 = eW1; b1 = eb1; W2 = eW2; b2 = eb2; }
    float h = 0.f;
    if (lane < 20) h = fmaxf(snr * W1[lane] + b1[lane], 0.f) * W2[lane];
#pragma unroll
    for (int off = 32; off > 0; off >>= 1) h += __shfl_down(h, off, 64);
    if (lane == 0) red[20 + wid] = 1.f / (1.f + expf(-(h + b2[0])));
  }
  // in-block graph build: slot assignment via LDS atomics. Any per-block
  // assignment is valid (LOO sums are commutative; slot identity links the
  // var-owner and check-owner through the same x_s address).
  int vl[VPT][CD];
#pragma unroll
  for (int i = 0; i < VPT; ++i) {
    int v = tid + i * TPB;
#pragma unroll
    for (int j = 0; j < CD; ++j) {
      int m    = row_idx[v * CD + j];
      int slot = atomicAdd(&cnt_s[m], 1);  // exactly RD=6 edges per check
      vl[i][j] = slot * M + m;             // check-major SoA address
    }
  }
  __syncthreads();   // MLP results ready; x_s zeros + slots visible
  const float g   = red[20];
  const float wiv = red[21];
  const float wev = red[22];
  const float omg = 1.f - g;
  float ell[VPT];
#pragma unroll
  for (int i = 0; i < VPT; ++i) ell[i] = wiv * ch[i];

  float v2c[VPT][CD] = {};       // V2C state (variable-owner registers)
  float c2v[CPT][RD] = {};       // C2V state (check-owner registers)

// per-edge variable-phase body: read We*c2v (WJ), update v2c, publish ±u
#define VAR_EDGE(i, J, WJ)                                              \
  {                                                                     \
    float nv  = fmaf(omg, v2c[i][J], g * (es - (WJ)));                  \
    v2c[i][J] = nv;                                                     \
    float l   = fminf(fmaxf(nv, -CLIP), CLIP);                          \
    float al  = fmaxf(fabsf(l), MIN_ABS);                               \
    float u   = 2.f * __builtin_amdgcn_rcpf(__expf(al) + 1.f);          \
    x_s[vl[i][J]] = (l < 0.f) ? -u : u; /* u = 1 - tanh(al/2) > 0 */    \
  }

  for (int t = 0; t < T; ++t) {
    // ---- variable phase: scattered b32 reads (We*c2v), publish ±u ----
#pragma unroll
    for (int i = 0; i < VPT; ++i) {
      int v    = tid + i * TPB;
      float w0 = x_s[vl[i][0]];
      float w1 = x_s[vl[i][1]];
      float w2 = x_s[vl[i][2]];
      float es = ell[i] + ((w0 + w1) + w2);
      if (t > 0) outT[((size_t)b * T + (t - 1)) * N + v] = es;
      VAR_EDGE(i, 0, w0)
      VAR_EDGE(i, 1, w1)
      VAR_EDGE(i, 2, w2)
    }
    __syncthreads();
    // ---- check phase: conflict-free b32 (lane t <-> check m), LOO ----
#pragma unroll
    for (int i = 0; i < CPT; ++i) {
      int m = tid + i * TPB;
      float usv[RD];
#pragma unroll
      for (int k = 0; k < RD; ++k) usv[k] = x_s[k * M + m];
      float u[RD], tt[RD];
      unsigned int sb[RD], s_all = 0u;
#pragma unroll
      for (int k = 0; k < RD; ++k) {
        float a = fabsf(usv[k]);
        u[k]  = a;
        tt[k] = 1.f - a;  // tanh(al/2)
        sb[k] = __float_as_uint(usv[k]) & 0x80000000u;
        s_all ^= sb[k];
      }
      // prefix (1 - prod) / prod over edges [0, k)
      float omp[RD + 1], Pp[RD + 1];
      omp[0] = 0.f; Pp[0] = 1.f;
#pragma unroll
      for (int k = 0; k < RD; ++k) {
        omp[k + 1] = fmaf(Pp[k], u[k], omp[k]);
        Pp[k + 1]  = Pp[k] * tt[k];
      }
      // suffix running (oms, Ps); iterate k = RD-1 .. 0
      float oms = 0.f, Ps = 1.f;
#pragma unroll
      for (int k = RD - 1; k >= 0; --k) {
        float om_loo = fmaf(Pp[k], oms, omp[k]);  // 1 - P_loo (stable)
        float P_loo  = Pp[k] * Ps;
        float den  = fmaf(FEPS, P_loo, om_loo);   // 1 - x, x = P_loo(1-eps)
        float num  = 2.f - den;                   // 1 + x (exact identity)
        float cnew = __logf(num * __builtin_amdgcn_rcpf(den));  // > 0
        cnew = __uint_as_float(__float_as_uint(cnew) ^ (s_all ^ sb[k]));
        float nc   = fmaf(omg, c2v[i][k], g * cnew);
        c2v[i][k]  = nc;
        x_s[k * M + m] = wev * nc;                // publish pre-scaled
        oms = fmaf(tt[k], oms, u[k]);             // extend suffix to [k, RD)
        Ps *= tt[k];
      }
    }
    __syncthreads();
  }
  // ---- final output row: out[T-1] = ell + full weighted col sum ----
#pragma unroll
  for (int i = 0; i < VPT; ++i) {
    int v   = tid + i * TPB;
    float s = (x_s[vl[i][0]] + x_s[vl[i][1]]) + x_s[vl[i][2]];
    outT[((size_t)b * T + (T - 1)) * N + v] = ell[i] + s;
  }
#undef VAR_EDGE
}

// ---- transpose out_T[b][t][v] -> out[t][v][b], tiled through LDS ----
__global__ __launch_bounds__(256) void k_tr(const float* __restrict__ outT,
                                            float* __restrict__ out) {
  __shared__ float tile[128 * 65];  // [b][v-tile], padded
  int t   = blockIdx.y;
  int v0  = blockIdx.x * 64;
  int tid = threadIdx.x;
#pragma unroll
  for (int r = 0; r < 32; ++r) {
    int bb = r * 4 + (tid >> 6);
    int v  = tid & 63;
    tile[bb * 65 + v] = outT[((size_t)bb * T + t) * N + v0 + v];
  }
  __syncthreads();
#pragma unroll
  for (int r = 0; r < 32; ++r) {
    int v  = r * 2 + (tid >> 7);
    int bb = tid & 127;
    // out is never re-read: non-temporal store keeps it out of L2
    __builtin_nontemporal_store(tile[bb * 65 + v],
                                &out[((size_t)t * N + v0 + v) * B + bb]);
  }
}

}  // namespace

extern "C" void kernel_launch(void* const* d_in, const int* in_sizes, int n_in,
                              void* d_out, int out_size, void* d_ws,
                              size_t ws_size, hipStream_t stream) {
  const float* chn = (const float*)d_in[0];
  const float* gW1 = (const float*)d_in[1];
  const float* gb1 = (const float*)d_in[2];
  const float* gW2 = (const float*)d_in[3];
  const float* gb2 = (const float*)d_in[4];
  const float* iW1 = (const float*)d_in[5];
  const float* ib1 = (const float*)d_in[6];
  const float* iW2 = (const float*)d_in[7];
  const float* ib2 = (const float*)d_in[8];
  const float* eW1 = (const float*)d_in[9];
  const float* eb1 = (const float*)d_in[10];
  const float* eW2 = (const float*)d_in[11];
  const float* eb2 = (const float*)d_in[12];
  const int* row_idx = (const int*)d_in[13];
  // d_in[14] (col_idx) = repeat(arange(N),3) by construction -> implicit.
  float* out = (float*)d_out;

  float* outT = (float*)d_ws;  // B*T*N floats (63 MB)

  k_fused<<<B, TPB, 0, stream>>>(chn, gW1, gb1, gW2, gb2, iW1, ib1, iW2, ib2,
                                 eW1, eb1, eW2, eb2, row_idx, outT);
  dim3 tg(N / 64, T);
  k_tr<<<tg, 256, 0, stream>>>(outT, out);
}